// Round 12
// baseline (522.651 us; speedup 1.0000x reference)
//
#include <hip/hip_runtime.h>
#include <cstdint>

// Problem constants
#define BB 16
#define NN 512
#define CC 768
#define HH 12
#define DD 64
#define HID 3072

typedef __bf16 bf16;
typedef __bf16 bf16x4 __attribute__((ext_vector_type(4)));
typedef __bf16 bf16x8 __attribute__((ext_vector_type(8)));
typedef float f32x4 __attribute__((ext_vector_type(4)));

__device__ __forceinline__ f32x4 mfma16(bf16x8 a, bf16x8 b, f32x4 c) {
    return __builtin_amdgcn_mfma_f32_16x16x32_bf16(a, b, c, 0, 0, 0);
}

__device__ __forceinline__ void g2l16(const bf16* g, bf16* l) {
    __builtin_amdgcn_global_load_lds(
        (const __attribute__((address_space(1))) void*)g,
        (__attribute__((address_space(3))) void*)l, 16, 0, 0);
}

template<int N>
__device__ __forceinline__ void wait_vm() {
    asm volatile("s_waitcnt vmcnt(%0)" :: "n"(N) : "memory");
}

// ---------------- device bodies (reused by fused launches) ----------------
__device__ __forceinline__ void cast_body(
    int i, const float* __restrict__ a, int na4, const float* __restrict__ b, bf16* __restrict__ dst)
{
    const float* s = (i < na4) ? a : b;
    int off = (i < na4) ? i : i - na4;
    f32x4 v = ((const f32x4*)s)[off];
    bf16x4 o;
    #pragma unroll
    for (int e = 0; e < 4; e++) o[e] = (bf16)v[e];
    ((bf16x4*)dst)[i] = o;
}

__device__ __forceinline__ void ln_body(
    int bid, const float* __restrict__ in, bf16* __restrict__ out,
    const float* __restrict__ g, const float* __restrict__ bt)
{
    int w = threadIdx.x >> 6, lane = threadIdx.x & 63;
    long t = bid * 4 + w;
    const float* xr = in + t * CC;
    float vals[12];
    float s = 0.f, sq = 0.f;
    #pragma unroll
    for (int i = 0; i < 3; i++) {
        int off = lane * 4 + i * 256;
        f32x4 v4 = *(const f32x4*)&xr[off];
        #pragma unroll
        for (int e = 0; e < 4; e++) {
            vals[i * 4 + e] = v4[e];
            s += v4[e]; sq += v4[e] * v4[e];
        }
    }
    #pragma unroll
    for (int m = 1; m < 64; m <<= 1) { s += __shfl_xor(s, m); sq += __shfl_xor(sq, m); }
    float mean = s * (1.f / 768.f);
    float var  = sq * (1.f / 768.f) - mean * mean;
    float rstd = rsqrtf(var + 1e-5f);
    bf16* orow = out + t * CC;
    #pragma unroll
    for (int i = 0; i < 3; i++) {
        int off = lane * 4 + i * 256;
        bf16x4 ov;
        #pragma unroll
        for (int e = 0; e < 4; e++)
            ov[e] = (bf16)((vals[i * 4 + e] - mean) * rstd * g[off + e] + bt[off + e]);
        *(bf16x4*)&orow[off] = ov;
    }
}

// LN2: read x1, write LN'd bf16 h2 only (NO x1 writeback — the g2*fc2_bias term is
// added by the OUT GEMM's z==0 blocks instead; saves a 25.2MB fp32 HBM write).
__device__ __forceinline__ void ln2_body(
    int bid, const float* __restrict__ x1, bf16* __restrict__ h2,
    const float* __restrict__ gt, const float* __restrict__ btt,
    const float* __restrict__ gf, const float* __restrict__ btf)
{
    int w = threadIdx.x >> 6, lane = threadIdx.x & 63;
    long u = bid * 4 + w;      // token 0..8191
    int b = (int)(u >> 9), n = (int)(u & 511);
    bool th = n < 256;
    const float* g  = th ? gt : gf;
    const float* bt = th ? btt : btf;
    long h2row = th ? ((long)b * 256 + n) : (4096 + (long)b * 256 + (n - 256));
    const float* xr = x1 + u * CC;
    float vals[12];
    float s = 0.f, sq = 0.f;
    #pragma unroll
    for (int i = 0; i < 3; i++) {
        int off = lane * 4 + i * 256;
        f32x4 v4 = *(const f32x4*)&xr[off];
        #pragma unroll
        for (int e = 0; e < 4; e++) {
            vals[i * 4 + e] = v4[e];
            s += v4[e]; sq += v4[e] * v4[e];
        }
    }
    #pragma unroll
    for (int m = 1; m < 64; m <<= 1) { s += __shfl_xor(s, m); sq += __shfl_xor(sq, m); }
    float mean = s * (1.f / 768.f);
    float var  = sq * (1.f / 768.f) - mean * mean;
    float rstd = rsqrtf(var + 1e-5f);
    bf16* orow = h2 + h2row * CC;
    #pragma unroll
    for (int i = 0; i < 3; i++) {
        int off = lane * 4 + i * 256;
        bf16x4 ov;
        #pragma unroll
        for (int e = 0; e < 4; e++)
            ov[e] = (bf16)((vals[i * 4 + e] - mean) * rstd * g[off + e] + bt[off + e]);
        *(bf16x4*)&orow[off] = ov;
    }
}

// bias precompute body, pre-arranged into MFMA C-fragment layout
// layout: element ((((h*8 + g)*4 + w)*8 + ch)*64 + lane)*16 + (ii*4 + t)
//   == bias[h][row = g*64 + w*16 + (lane>>4)*4 + ii][col = ch*64 + t*16 + (lane&15)]
__device__ __forceinline__ void bias_body(
    int flat, const int* __restrict__ rpi, const float* __restrict__ table, bf16* __restrict__ bb)
{
    int lane = flat & 63;
    int ch   = (flat >> 6) & 7;
    int w    = (flat >> 9) & 3;
    int g    = (flat >> 11) & 7;
    int h    = flat >> 14;
    int row0 = g * 64 + w * 16 + (lane >> 4) * 4;
    int col0 = ch * 64 + (lane & 15);
    bf16x8 v0, v1;
    #pragma unroll
    for (int ii = 0; ii < 4; ii++) {
        #pragma unroll
        for (int t = 0; t < 4; t++) {
            int r = rpi[(row0 + ii) * NN + col0 + t * 16];
            bf16 val = (bf16)table[r * HH + h];
            if (ii < 2) v0[ii * 4 + t] = val;
            else        v1[(ii - 2) * 4 + t] = val;
        }
    }
    bf16* dst = bb + (long)flat * 16;
    *(bf16x8*)dst = v0;
    *(bf16x8*)(dst + 8) = v1;
}

// ---------------- standalone cast ----------------
__global__ __launch_bounds__(256) void cast2_kernel(
    const float* __restrict__ a, int na4, const float* __restrict__ b, bf16* __restrict__ dst)
{
    cast_body(blockIdx.x * 256 + threadIdx.x, a, na4, b, dst);
}

// ---------------- LN1 fused with Wqkv cast AND bias precompute ----------------
// bids [0,2048): LN1; [2048,3776): Wqkv cast; [3776,4544): bias table (bbt = h + TOKC,
// coexists with h in d_out — h occupies first 12.6MB, bbt the next 6.3MB).
__global__ __launch_bounds__(256) void ln1_cast_kernel(
    const float* __restrict__ x, bf16* __restrict__ h,
    const float* __restrict__ g, const float* __restrict__ bt,
    const float* __restrict__ Wqkv, bf16* __restrict__ wqkv,
    const int* __restrict__ rpi, const float* __restrict__ rtab, bf16* __restrict__ bb)
{
    int bid = blockIdx.x;
    if (bid < 2048)      ln_body(bid, x, h, g, bt);
    else if (bid < 3776) cast_body((bid - 2048) * 256 + threadIdx.x, Wqkv, 442368, nullptr, wqkv);
    else                 bias_body((bid - 3776) * 256 + threadIdx.x, rpi, rtab, bb);
}

// ---------------- LN2 fused with t-half weight-pair cast ----------------
__global__ __launch_bounds__(256) void ln2_cast_kernel(
    const float* __restrict__ x1, bf16* __restrict__ h2,
    const float* __restrict__ gt, const float* __restrict__ btt,
    const float* __restrict__ gf, const float* __restrict__ btf,
    const float* __restrict__ f1W, const float* __restrict__ f2W, bf16* __restrict__ w1)
{
    int bid = blockIdx.x;
    if (bid < 2048) ln2_body(bid, x1, h2, gt, btt, gf, btf);
    else            cast_body((bid - 2048) * 256 + threadIdx.x, f1W, (HID * CC) / 4, f2W, w1);
}

// ------- BMxBN MFMA GEMM, single-barrier DEPTH-ring, counted vmcnt: C = A @ Bt^T -------
// SWZ=1 (T2, rule 21): linear LDS dest + inverse-swizzled global SOURCE + swizzled read
// (kept on HBM-streaming PROJ/OUT; off for L2-resident QKV/GELU).
// CASTN>0: grid.y extended past gyGemm; trailing blocks cast 589824 f32x4 items (one fc
// weight), CASTN items/thread — hides f-half weight casts under OUT-t / GELU-f tails.
// MODE_OUT: cbias = fc2 bias, added (scaled by gamma) ONLY by blockIdx.z==0 blocks so each
// output element receives it exactly once (replaces the ln2 x1-writeback).
enum { MODE_QKV = 0, MODE_PROJ = 1, MODE_GELU = 2, MODE_OUT = 3 };

template<int MODE, int K, int KCHUNK, int BM, int BN, int DEPTH, int SWZ, int CASTN>
__global__ __launch_bounds__(256, 3) void gemm_bt(
    const bf16* __restrict__ A, const bf16* __restrict__ Btb,
    const float* __restrict__ cbias, const float* residf,
    const float* __restrict__ gamma,
    bf16* __restrict__ outb0, bf16* __restrict__ outb1, bf16* __restrict__ outb2,
    float* outf, int rowbase,
    const float* __restrict__ castsrc, bf16* __restrict__ castdst, int gyGemm)
{
    constexpr int AR = BM / 64;    // staging rounds (256 threads x 16B covers 64 rows x 32 cols)
    constexpr int BR = BN / 64;
    constexpr int L  = AR + BR;    // vmem loads per tile per thread
    constexpr int VM = (DEPTH - 2) * L;  // counted: tile t landed, DEPTH-2 newer tiles in flight
    constexpr int NT = KCHUNK / 32;
    static_assert(NT > DEPTH, "");
    constexpr int FM = BM / 32;    // frags per wave (m)
    constexpr int FN = BN / 32;
    __shared__ bf16 lsA[DEPTH][BM * 32];
    __shared__ bf16 lsB[DEPTH][BN * 32];
    int tid = threadIdx.x;
    if (CASTN > 0 && (int)blockIdx.y >= gyGemm) {
        int cb = ((blockIdx.y - gyGemm) * gridDim.x + blockIdx.x) * gridDim.z + blockIdx.z;
        int base = cb * (256 * CASTN);
        #pragma unroll
        for (int i = 0; i < CASTN; i++)
            cast_body(base + i * 256 + tid, castsrc, 589824, nullptr, castdst);
        return;
    }
    int lane = tid & 63, w = tid >> 6;
    int wm = w & 1, wn = w >> 1;
    int gx = gridDim.x;
    int nwg = gx * gyGemm;
    int flat = blockIdx.y * gx + blockIdx.x;
    // XCD-aware bijective swizzle (nwg % 8 == 0 for every launch in this file)
    int cpx = nwg >> 3;
    flat = (flat & 7) * cpx + (flat >> 3);
    int bx = flat % gx, by = flat / gx;
    long m0 = (long)by * BM;
    long n0 = (long)bx * BN;
    long kb = (long)blockIdx.z * KCHUNK;
    f32x4 acc[FM][FN] = {};
    const bf16* Ab = A + m0 * K + kb;
    const bf16* Bb = Btb + n0 * K + kb;
    int r0 = tid >> 2;
    int la = lane & 15;
    // SWZ=0: natural chunk; SWZ=1: inverse-swizzled source / swizzled read (see header)
    int kgS = SWZ ? ((tid & 3) ^ ((tid >> 3) & 3)) * 8 : (tid & 3) * 8;
    int hkS = SWZ ? (((lane >> 4) ^ ((lane >> 1) & 3))) * 8 : (lane >> 4) * 8;

#define STAGE(DB, KT)                                                                        \
    {                                                                                        \
        long sk_ = (long)(KT) * 32;                                                          \
        _Pragma("unroll")                                                                    \
        for (int rr = 0; rr < AR; rr++)                                                      \
            g2l16(Ab + (long)(r0 + rr * 64) * K + sk_ + kgS, lsA[DB] + (tid + rr * 256) * 8);\
        _Pragma("unroll")                                                                    \
        for (int rr = 0; rr < BR; rr++)                                                      \
            g2l16(Bb + (long)(r0 + rr * 64) * K + sk_ + kgS, lsB[DB] + (tid + rr * 256) * 8);\
    }

    // prologue: stage tiles 0..DEPTH-2 (one ring slot stays free), no waits
    #pragma unroll
    for (int d = 0; d < DEPTH - 1; d++) STAGE(d, d)

    int p = 0;
    for (int t = 0; t < NT - 1; t++) {
        wait_vm<VM>();                          // my share of tile t landed
        __builtin_amdgcn_sched_barrier(0);
        __builtin_amdgcn_s_barrier();           // everyone's share landed; t-1 reads retired
        __builtin_amdgcn_sched_barrier(0);
        bf16x8 af[FM], bfr[FN];
        #pragma unroll
        for (int mi = 0; mi < FM; mi++) af[mi]  = *(bf16x8*)&lsA[p][(wm * (BM / 2) + mi * 16 + la) * 32 + hkS];
        #pragma unroll
        for (int ni = 0; ni < FN; ni++) bfr[ni] = *(bf16x8*)&lsB[p][(wn * (BN / 2) + ni * 16 + la) * 32 + hkS];
        if (t + DEPTH - 1 < NT) {
            int pd = p + DEPTH - 1; if (pd >= DEPTH) pd -= DEPTH;   // buffer freed at t-1
            STAGE(pd, t + DEPTH - 1)
        }
        asm volatile("s_waitcnt lgkmcnt(0)" ::: "memory");
        __builtin_amdgcn_sched_barrier(0);
        __builtin_amdgcn_s_setprio(1);
        #pragma unroll
        for (int mi = 0; mi < FM; mi++)
            #pragma unroll
            for (int ni = 0; ni < FN; ni++)
                acc[mi][ni] = mfma16(af[mi], bfr[ni], acc[mi][ni]);
        __builtin_amdgcn_s_setprio(0);
        p = (p + 1 == DEPTH) ? 0 : p + 1;
    }
    // last iteration: nothing left in flight to count -> full drain
    {
        wait_vm<0>();
        __builtin_amdgcn_sched_barrier(0);
        __builtin_amdgcn_s_barrier();
        __builtin_amdgcn_sched_barrier(0);
        bf16x8 af[FM], bfr[FN];
        #pragma unroll
        for (int mi = 0; mi < FM; mi++) af[mi]  = *(bf16x8*)&lsA[p][(wm * (BM / 2) + mi * 16 + la) * 32 + hkS];
        #pragma unroll
        for (int ni = 0; ni < FN; ni++) bfr[ni] = *(bf16x8*)&lsB[p][(wn * (BN / 2) + ni * 16 + la) * 32 + hkS];
        asm volatile("s_waitcnt lgkmcnt(0)" ::: "memory");
        __builtin_amdgcn_sched_barrier(0);
        __builtin_amdgcn_s_setprio(1);
        #pragma unroll
        for (int mi = 0; mi < FM; mi++)
            #pragma unroll
            for (int ni = 0; ni < FN; ni++)
                acc[mi][ni] = mfma16(af[mi], bfr[ni], acc[mi][ni]);
        __builtin_amdgcn_s_setprio(0);
    }
#undef STAGE

    int q4 = (lane >> 4) * 4;
    // QKV: the whole block maps into exactly one of q/k/v (768 % BN == 0)
    int sblk = 0, cb0 = 0;
    if constexpr (MODE == MODE_QKV) {
        sblk = (int)(n0 / CC);
        cb0  = (int)n0 - sblk * CC;
    }
    #pragma unroll
    for (int mi = 0; mi < FM; mi++) {
        #pragma unroll
        for (int ni = 0; ni < FN; ni++) {
            long rb = m0 + wm * (BM / 2) + mi * 16 + q4;
            long c  = n0 + wn * (BN / 2) + ni * 16 + la;
            #pragma unroll
            for (int i = 0; i < 4; i++) {
                long r = rb + i;
                float v = acc[mi][ni][i];
                if (MODE == MODE_QKV) {
                    int rem = cb0 + wn * (BN / 2) + ni * 16 + la;
                    int hh = rem >> 6, d = rem & 63;
                    long b = r >> 9, n = r & 511;
                    long dst = (((b * HH + hh) << 9) + n) * 64 + d;
                    if (sblk == 0)      outb0[dst] = (bf16)(v * 0.125f);
                    else if (sblk == 1) outb1[dst] = (bf16)v;
                    else                outb2[dst] = (bf16)v;
                } else if (MODE == MODE_PROJ) {
                    float val = v + cbias[c];
                    long idx = r * CC + c;
                    outf[idx] = residf[idx] + gamma[c] * val;
                } else if (MODE == MODE_GELU) {
                    float val = v + cbias[c];
                    float gl = 0.5f * val * (1.f + erff(val * 0.70710678118f));
                    outb0[r * (long)HID + c] = (bf16)gl;
                } else {  // MODE_OUT: split-K atomic accumulate; z==0 adds fc2 bias once
                    float add = (blockIdx.z == 0) ? cbias[c] : 0.f;
                    long grow = (r >> 8) * NN + (r & 255) + rowbase;
                    atomicAdd(outf + grow * CC + c, gamma[c] * (v + add));
                }
            }
        }
    }
}

// ---------------- Flash attention: 128 q-rows per block (two 16-row tiles per wave) ----------------
// grid = b(16) x qt(4) x h(12).  K/V staged once per chunk, reused by both q-sets.
// bias read as 2x16B coalesced loads from pre-arranged fragment layout.
// row-sum l accumulated via mfma(P, ones) (rides the MFMA pipe; no sum-shuffles).
__global__ __launch_bounds__(256, 3) void attn_kernel(
    const bf16* __restrict__ q, const bf16* __restrict__ k, const bf16* __restrict__ v,
    const bf16* __restrict__ bb, bf16* __restrict__ o)
{
    __shared__ bf16 lsK[64 * 72];
    __shared__ bf16 lsVT[64 * 68];
    __shared__ bf16 lsP[4][2][16 * 76];
    int tid = threadIdx.x, lane = tid & 63, w = tid >> 6;
    int b  = blockIdx.x & 15;
    int qt = (blockIdx.x >> 4) & 3;
    int h  = blockIdx.x >> 6;
    long base = (long)(b * HH + h) * NN * DD;
    int la = lane & 15, hi = lane >> 4;
    int qr0 = qt * 128 + w * 16;           // set A rows; set B = +64
    // bias base for (h, granule=qt*2, w); granule stride = 4*8*1024 = 32768
    const bf16* bb0 = bb + ((long)((h * 8 + qt * 2) * 4 + w) * 8) * 1024 + lane * 16;

    bf16x8 qA0 = *(const bf16x8*)&q[base + (long)(qr0 + la) * 64 + hi * 8];
    bf16x8 qA1 = *(const bf16x8*)&q[base + (long)(qr0 + la) * 64 + 32 + hi * 8];
    bf16x8 qB0 = *(const bf16x8*)&q[base + (long)(qr0 + 64 + la) * 64 + hi * 8];
    bf16x8 qB1 = *(const bf16x8*)&q[base + (long)(qr0 + 64 + la) * 64 + 32 + hi * 8];
    f32x4 ofA[4] = {}, ofB[4] = {};
    f32x4 lfA = {}, lfB = {};
    float mA[4], mB[4];
    #pragma unroll
    for (int i = 0; i < 4; i++) { mA[i] = -1e30f; mB[i] = -1e30f; }
    bf16x8 ones;
    #pragma unroll
    for (int e = 0; e < 8; e++) ones[e] = (bf16)1.0f;

    int jr = tid >> 2, dg16 = (tid & 3) * 16;
    for (int ch = 0; ch < 8; ch++) {
        int j0 = ch * 64;
        const bf16* krow = &k[base + (long)(j0 + jr) * 64 + dg16];
        *(bf16x8*)&lsK[jr * 72 + dg16]     = *(const bf16x8*)krow;
        *(bf16x8*)&lsK[jr * 72 + dg16 + 8] = *(const bf16x8*)(krow + 8);
        const bf16* vrow = &v[base + (long)(j0 + jr) * 64 + dg16];
        bf16x8 v0 = *(const bf16x8*)vrow;
        bf16x8 v1 = *(const bf16x8*)(vrow + 8);
        #pragma unroll
        for (int e = 0; e < 8; e++) {
            lsVT[(dg16 + e) * 68 + jr]     = v0[e];
            lsVT[(dg16 + 8 + e) * 68 + jr] = v1[e];
        }
        __syncthreads();

        // QK^T, K-frags shared by both q-sets
        f32x4 sA[4] = {}, sB[4] = {};
        #pragma unroll
        for (int t = 0; t < 4; t++) {
            bf16x8 kf0 = *(bf16x8*)&lsK[(t * 16 + la) * 72 + hi * 8];
            bf16x8 kf1 = *(bf16x8*)&lsK[(t * 16 + la) * 72 + 32 + hi * 8];
            sA[t] = mfma16(qA0, kf0, sA[t]);
            sA[t] = mfma16(qA1, kf1, sA[t]);
            sB[t] = mfma16(qB0, kf0, sB[t]);
            sB[t] = mfma16(qB1, kf1, sB[t]);
        }
        // bias: 2x16B coalesced loads per set
        {
            const bf16* bpA = bb0 + ch * 1024;
            const bf16* bpB = bpA + 32768;
            bf16x8 a0 = *(const bf16x8*)bpA, a1 = *(const bf16x8*)(bpA + 8);
            bf16x8 c0 = *(const bf16x8*)bpB, c1 = *(const bf16x8*)(bpB + 8);
            #pragma unroll
            for (int t = 0; t < 4; t++) {
                sA[t][0] += (float)a0[t];     sA[t][1] += (float)a0[4 + t];
                sA[t][2] += (float)a1[t];     sA[t][3] += (float)a1[4 + t];
                sB[t][0] += (float)c0[t];     sB[t][1] += (float)c0[4 + t];
                sB[t][2] += (float)c1[t];     sB[t][3] += (float)c1[4 + t];
            }
        }
        // online softmax (max-reduce via shuffles; sum deferred to mfma(P, ones))
        #define SM_SET(S, M, OF, LF, PSET)                                               \
        {                                                                                \
            float alpha[4];                                                              \
            _Pragma("unroll")                                                            \
            for (int i = 0; i < 4; i++) {                                                \
                float mx = fmaxf(fmaxf(S[0][i], S[1][i]), fmaxf(S[2][i], S[3][i]));      \
                _Pragma("unroll")                                                        \
                for (int msk = 1; msk < 16; msk <<= 1) mx = fmaxf(mx, __shfl_xor(mx, msk)); \
                float mn = fmaxf(M[i], mx);                                              \
                alpha[i] = __expf(M[i] - mn);                                            \
                M[i] = mn;                                                               \
                _Pragma("unroll")                                                        \
                for (int t = 0; t < 4; t++) S[t][i] = __expf(S[t][i] - mn);              \
            }                                                                            \
            _Pragma("unroll")                                                            \
            for (int t = 0; t < 4; t++) {                                                \
                _Pragma("unroll")                                                        \
                for (int i = 0; i < 4; i++) OF[t][i] *= alpha[i];                        \
            }                                                                            \
            _Pragma("unroll")                                                            \
            for (int i = 0; i < 4; i++) LF[i] *= alpha[i];                               \
            _Pragma("unroll")                                                            \
            for (int i = 0; i < 4; i++) {                                                \
                _Pragma("unroll")                                                        \
                for (int t = 0; t < 4; t++)                                              \
                    lsP[w][PSET][(hi * 4 + i) * 76 + t * 16 + la] = (bf16)S[t][i];       \
            }                                                                            \
        }
        SM_SET(sA, mA, ofA, lfA, 0)
        SM_SET(sB, mB, ofB, lfB, 1)
        #undef SM_SET

        bf16x8 pA0 = *(bf16x8*)&lsP[w][0][la * 76 + hi * 8];
        bf16x8 pA1 = *(bf16x8*)&lsP[w][0][la * 76 + 32 + hi * 8];
        bf16x8 pB0 = *(bf16x8*)&lsP[w][1][la * 76 + hi * 8];
        bf16x8 pB1 = *(bf16x8*)&lsP[w][1][la * 76 + 32 + hi * 8];
        #pragma unroll
        for (int t = 0; t < 4; t++) {
            bf16x8 vf0 = *(bf16x8*)&lsVT[(t * 16 + la) * 68 + hi * 8];
            bf16x8 vf1 = *(bf16x8*)&lsVT[(t * 16 + la) * 68 + 32 + hi * 8];
            ofA[t] = mfma16(pA0, vf0, ofA[t]);
            ofA[t] = mfma16(pA1, vf1, ofA[t]);
            ofB[t] = mfma16(pB0, vf0, ofB[t]);
            ofB[t] = mfma16(pB1, vf1, ofB[t]);
        }
        lfA = mfma16(pA0, ones, lfA);
        lfA = mfma16(pA1, ones, lfA);
        lfB = mfma16(pB0, ones, lfB);
        lfB = mfma16(pB1, ones, lfB);
        __syncthreads();
    }
    float invA[4], invB[4];
    #pragma unroll
    for (int i = 0; i < 4; i++) { invA[i] = 1.f / lfA[i]; invB[i] = 1.f / lfB[i]; }
    #pragma unroll
    for (int t = 0; t < 4; t++) {
        #pragma unroll
        for (int i = 0; i < 4; i++) {
            long rowA = (long)b * NN + qr0 + hi * 4 + i;
            o[rowA * CC + h * 64 + t * 16 + la]        = (bf16)(ofA[t][i] * invA[i]);
            o[(rowA + 64) * CC + h * 64 + t * 16 + la] = (bf16)(ofB[t][i] * invB[i]);
        }
    }
}

extern "C" void kernel_launch(void* const* d_in, const int* in_sizes, int n_in,
                              void* d_out, int out_size, void* d_ws, size_t ws_size,
                              hipStream_t stream)
{
    const float* x     = (const float*)d_in[0];
    const int*   rpi   = (const int*)d_in[2];
    const float* Wqkv  = (const float*)d_in[3];
    const float* Wproj = (const float*)d_in[4];
    const float* bproj = (const float*)d_in[5];
    const float* rtab  = (const float*)d_in[6];
    const float* ln1g  = (const float*)d_in[7];
    const float* ln1b  = (const float*)d_in[8];
    const float* g1    = (const float*)d_in[9];
    const float* g2    = (const float*)d_in[10];
    const float* ln2tg = (const float*)d_in[11];
    const float* ln2tb = (const float*)d_in[12];
    const float* f1tW  = (const float*)d_in[13];
    const float* f1tb  = (const float*)d_in[14];
    const float* f2tW  = (const float*)d_in[15];
    const float* f2tb  = (const float*)d_in[16];
    const float* ln2fg = (const float*)d_in[17];
    const float* ln2fb = (const float*)d_in[18];
    const float* f1fW  = (const float*)d_in[19];
    const float* f1fb  = (const float*)d_in[20];
    const float* f2fW  = (const float*)d_in[21];
    const float* f2fb  = (const float*)d_in[22];
    float* out = (float*)d_out;

    // ws: 4 regions x 12.58MB bf16 = 50.33MB.
    //  rA: q -> wpro -> h2 (w1f cast over dead t-half during OUT-t)
    //  rB: k -> hg lo     rC: v -> hg hi
    //  rD: Wqkv(bf16) -> o -> [w1t|w2t] -> w2f over dead w1t during GELU-f
    // d_out: [0,12.6MB) h; [12.6,18.9MB) bias table; then x1 (fp32) overwrites all
    char* ws = (char*)d_ws;
    const long TOKC = (long)BB * NN * CC;        // 6291456
    const int  NFC  = HID * CC;                  // 2359296
    bf16* rA = (bf16*)ws;
    bf16* rB = rA + TOKC;
    bf16* rC = rB + TOKC;
    bf16* rD = rC + TOKC;

    bf16 *qb = rA, *kb = rB, *vb = rC, *o = rD;
    bf16  *h    = (bf16*)d_out;
    bf16  *bbt  = h + TOKC;        // coexists with h (d_out is 25.2MB fp32 out)
    float *x1   = out;
    bf16  *wqkv = rD;     // before o
    bf16  *wpro = rA;     // after q dies
    bf16  *h2   = rA;     // after wpro dies
    bf16  *hg   = rB;     // spans rB+rC
    bf16  *w1t  = rD;     // [w1t | w2t] pair cast by ln2_cast (o dead)
    bf16  *w2t  = rD + NFC;
    bf16  *w1f  = rA;     // cast into dead t-half h2 region during OUT-t
    bf16  *w2f  = rD;     // cast over dead w1t during GELU-f

    // 1. LN1 (fp32 x -> bf16 h) + Wqkv cast (rD) + bias table (d_out+12.6MB) in one launch
    ln1_cast_kernel<<<2048 + 1728 + 768, 256, 0, stream>>>(x, h, ln1g, ln1b, Wqkv, wqkv, rpi, rtab, bbt);
    // 2. QKV projection (L2-resident: SWZ=0)
    {
        dim3 g(2304 / 128, 8192 / 128, 1);
        gemm_bt<MODE_QKV, 768, 768, 128, 128, 3, 0, 0><<<g, 256, 0, stream>>>(
            h, wqkv, nullptr, nullptr, nullptr, qb, kb, vb, nullptr, 0, nullptr, nullptr, 64);
    }
    // 3. attention (reads rA,rB,rC,bbt; writes o=rD; wqkv dead)
    attn_kernel<<<BB * 4 * HH, 256, 0, stream>>>(qb, kb, vb, bbt, o);
    // 4. cast Wproj -> bf16 (rA; q dead)
    cast2_kernel<<<576, 256, 0, stream>>>(Wproj, 147456, nullptr, wpro);
    // 5. proj + residual -> x1 (HBM-streaming: SWZ=1); 64x128 tile -> 768 blocks (3/CU)
    {
        dim3 g(768 / 128, 8192 / 64, 1);
        gemm_bt<MODE_PROJ, 768, 768, 64, 128, 4, 1, 0><<<g, 256, 0, stream>>>(
            o, wpro, bproj, x, g1, nullptr, nullptr, nullptr, x1, 0, nullptr, nullptr, 128);
    }
    // 6. LN2 both halves -> h2 (rA; wpro dead; x1 read-only now); cast (f1tW,f2tW) -> rD
    ln2_cast_kernel<<<2048 + 4608, 256, 0, stream>>>(x1, h2, ln2tg, ln2tb, ln2fg, ln2fb,
                                                     f1tW, f2tW, w1t);
    // 7. GELU-t (SWZ=0): h2[0:4096] @ w1t -> hg
    {
        dim3 ga(3072 / 128, 4096 / 128, 1);
        gemm_bt<MODE_GELU, 768, 768, 128, 128, 3, 0, 0><<<ga, 256, 0, stream>>>(
            h2, w1t, f1tb, nullptr, nullptr, hg, nullptr, nullptr, nullptr, 0, nullptr, nullptr, 32);
    }
    // 8. OUT-t (SWZ=1, split-K=2, z==0 adds g2*f2tb) + folded w1f cast -> rA:
    //    grid (6, 64 gemm + 64 cast, 2); cast blocks = 6*64*2 = 768, 3 items/thread.
    {
        dim3 gb(768 / 128, 64 + 64, 2);
        gemm_bt<MODE_OUT, 3072, 1536, 64, 128, 4, 1, 3><<<gb, 256, 0, stream>>>(
            hg, w2t, f2tb, nullptr, g2, nullptr, nullptr, nullptr, out, 0, f1fW, w1f, 64);
    }
    // 9. GELU-f (SWZ=0) + folded w2f cast -> rD[0] (w1t dead after GELU-t):
    //    grid (24, 32 gemm + 12 cast); cast blocks = 24*12 = 288, 8 items/thread.
    {
        dim3 ga(3072 / 128, 32 + 12, 1);
        gemm_bt<MODE_GELU, 768, 768, 128, 128, 3, 0, 8><<<ga, 256, 0, stream>>>(
            h2 + (long)4096 * CC, w1f, f1fb, nullptr, nullptr, hg, nullptr, nullptr, nullptr, 0, f2fW, w2f, 32);
    }
    // 10. OUT-f (SWZ=1, split-K=2, z==0 adds g2*f2fb), B = w2f at rD[0]
    {
        dim3 gb(768 / 128, 4096 / 64, 2);
        gemm_bt<MODE_OUT, 3072, 1536, 64, 128, 4, 1, 0><<<gb, 256, 0, stream>>>(
            hg, w2f, f2fb, nullptr, g2, nullptr, nullptr, nullptr, out, 256, nullptr, nullptr, 64);
    }
}

// Round 13
// 448.841 us; speedup vs baseline: 1.1644x; 1.1644x over previous
//
#include <hip/hip_runtime.h>
#include <cstdint>

// Problem constants
#define BB 16
#define NN 512
#define CC 768
#define HH 12
#define DD 64
#define HID 3072

typedef __bf16 bf16;
typedef __bf16 bf16x4 __attribute__((ext_vector_type(4)));
typedef __bf16 bf16x8 __attribute__((ext_vector_type(8)));
typedef float f32x4 __attribute__((ext_vector_type(4)));

__device__ __forceinline__ f32x4 mfma16(bf16x8 a, bf16x8 b, f32x4 c) {
    return __builtin_amdgcn_mfma_f32_16x16x32_bf16(a, b, c, 0, 0, 0);
}

__device__ __forceinline__ void g2l16(const bf16* g, bf16* l) {
    __builtin_amdgcn_global_load_lds(
        (const __attribute__((address_space(1))) void*)g,
        (__attribute__((address_space(3))) void*)l, 16, 0, 0);
}

template<int N>
__device__ __forceinline__ void wait_vm() {
    asm volatile("s_waitcnt vmcnt(%0)" :: "n"(N) : "memory");
}

// ---------------- device bodies (reused by fused launches) ----------------
__device__ __forceinline__ void cast_body(
    int i, const float* __restrict__ a, int na4, const float* __restrict__ b, bf16* __restrict__ dst)
{
    const float* s = (i < na4) ? a : b;
    int off = (i < na4) ? i : i - na4;
    f32x4 v = ((const f32x4*)s)[off];
    bf16x4 o;
    #pragma unroll
    for (int e = 0; e < 4; e++) o[e] = (bf16)v[e];
    ((bf16x4*)dst)[i] = o;
}

__device__ __forceinline__ void ln_body(
    int bid, const float* __restrict__ in, bf16* __restrict__ out,
    const float* __restrict__ g, const float* __restrict__ bt)
{
    int w = threadIdx.x >> 6, lane = threadIdx.x & 63;
    long t = bid * 4 + w;
    const float* xr = in + t * CC;
    float vals[12];
    float s = 0.f, sq = 0.f;
    #pragma unroll
    for (int i = 0; i < 3; i++) {
        int off = lane * 4 + i * 256;
        f32x4 v4 = *(const f32x4*)&xr[off];
        #pragma unroll
        for (int e = 0; e < 4; e++) {
            vals[i * 4 + e] = v4[e];
            s += v4[e]; sq += v4[e] * v4[e];
        }
    }
    #pragma unroll
    for (int m = 1; m < 64; m <<= 1) { s += __shfl_xor(s, m); sq += __shfl_xor(sq, m); }
    float mean = s * (1.f / 768.f);
    float var  = sq * (1.f / 768.f) - mean * mean;
    float rstd = rsqrtf(var + 1e-5f);
    bf16* orow = out + t * CC;
    #pragma unroll
    for (int i = 0; i < 3; i++) {
        int off = lane * 4 + i * 256;
        bf16x4 ov;
        #pragma unroll
        for (int e = 0; e < 4; e++)
            ov[e] = (bf16)((vals[i * 4 + e] - mean) * rstd * g[off + e] + bt[off + e]);
        *(bf16x4*)&orow[off] = ov;
    }
}

// LN2: writes LN'd bf16 h2 AND x1 += g2*fc2_bias (the writeback keeps `out` lines warm
// and in clean single-writer state right before the MLP's atomic accumulation — removing
// it regressed OUT by ~19us/dispatch in round-12's A/B).
__device__ __forceinline__ void ln2_body(
    int bid, float* x1, bf16* __restrict__ h2,
    const float* __restrict__ gt, const float* __restrict__ btt,
    const float* __restrict__ gf, const float* __restrict__ btf,
    const float* __restrict__ g2, const float* __restrict__ b2t, const float* __restrict__ b2f)
{
    int w = threadIdx.x >> 6, lane = threadIdx.x & 63;
    long u = bid * 4 + w;      // token 0..8191
    int b = (int)(u >> 9), n = (int)(u & 511);
    bool th = n < 256;
    const float* g  = th ? gt : gf;
    const float* bt = th ? btt : btf;
    const float* b2 = th ? b2t : b2f;
    long h2row = th ? ((long)b * 256 + n) : (4096 + (long)b * 256 + (n - 256));
    float* xr = x1 + u * CC;
    float vals[12];
    float s = 0.f, sq = 0.f;
    #pragma unroll
    for (int i = 0; i < 3; i++) {
        int off = lane * 4 + i * 256;
        f32x4 v4 = *(const f32x4*)&xr[off];
        #pragma unroll
        for (int e = 0; e < 4; e++) {
            vals[i * 4 + e] = v4[e];
            s += v4[e]; sq += v4[e] * v4[e];
        }
    }
    #pragma unroll
    for (int m = 1; m < 64; m <<= 1) { s += __shfl_xor(s, m); sq += __shfl_xor(sq, m); }
    float mean = s * (1.f / 768.f);
    float var  = sq * (1.f / 768.f) - mean * mean;
    float rstd = rsqrtf(var + 1e-5f);
    bf16* orow = h2 + h2row * CC;
    #pragma unroll
    for (int i = 0; i < 3; i++) {
        int off = lane * 4 + i * 256;
        bf16x4 ov;
        f32x4 wv;
        #pragma unroll
        for (int e = 0; e < 4; e++) {
            ov[e] = (bf16)((vals[i * 4 + e] - mean) * rstd * g[off + e] + bt[off + e]);
            wv[e] = vals[i * 4 + e] + g2[off + e] * b2[off + e];
        }
        *(bf16x4*)&orow[off] = ov;
        *(f32x4*)&xr[off] = wv;
    }
}

// bias precompute body, pre-arranged into MFMA C-fragment layout
// layout: element ((((h*8 + g)*4 + w)*8 + ch)*64 + lane)*16 + (ii*4 + t)
//   == bias[h][row = g*64 + w*16 + (lane>>4)*4 + ii][col = ch*64 + t*16 + (lane&15)]
__device__ __forceinline__ void bias_body(
    int flat, const int* __restrict__ rpi, const float* __restrict__ table, bf16* __restrict__ bb)
{
    int lane = flat & 63;
    int ch   = (flat >> 6) & 7;
    int w    = (flat >> 9) & 3;
    int g    = (flat >> 11) & 7;
    int h    = flat >> 14;
    int row0 = g * 64 + w * 16 + (lane >> 4) * 4;
    int col0 = ch * 64 + (lane & 15);
    bf16x8 v0, v1;
    #pragma unroll
    for (int ii = 0; ii < 4; ii++) {
        #pragma unroll
        for (int t = 0; t < 4; t++) {
            int r = rpi[(row0 + ii) * NN + col0 + t * 16];
            bf16 val = (bf16)table[r * HH + h];
            if (ii < 2) v0[ii * 4 + t] = val;
            else        v1[(ii - 2) * 4 + t] = val;
        }
    }
    bf16* dst = bb + (long)flat * 16;
    *(bf16x8*)dst = v0;
    *(bf16x8*)(dst + 8) = v1;
}

// ---------------- standalone cast ----------------
__global__ __launch_bounds__(256) void cast2_kernel(
    const float* __restrict__ a, int na4, const float* __restrict__ b, bf16* __restrict__ dst)
{
    cast_body(blockIdx.x * 256 + threadIdx.x, a, na4, b, dst);
}

// ---------------- LN1 fused with Wqkv cast AND bias precompute ----------------
// bids [0,2048): LN1; [2048,3776): Wqkv cast; [3776,4544): bias table (bbt = h + TOKC,
// coexists with h in d_out — h occupies first 12.6MB, bbt the next 6.3MB).
__global__ __launch_bounds__(256) void ln1_cast_kernel(
    const float* __restrict__ x, bf16* __restrict__ h,
    const float* __restrict__ g, const float* __restrict__ bt,
    const float* __restrict__ Wqkv, bf16* __restrict__ wqkv,
    const int* __restrict__ rpi, const float* __restrict__ rtab, bf16* __restrict__ bb)
{
    int bid = blockIdx.x;
    if (bid < 2048)      ln_body(bid, x, h, g, bt);
    else if (bid < 3776) cast_body((bid - 2048) * 256 + threadIdx.x, Wqkv, 442368, nullptr, wqkv);
    else                 bias_body((bid - 3776) * 256 + threadIdx.x, rpi, rtab, bb);
}

// ---------------- LN2 fused with t-half weight-pair cast ----------------
__global__ __launch_bounds__(256) void ln2_cast_kernel(
    float* x1, bf16* __restrict__ h2,
    const float* __restrict__ gt, const float* __restrict__ btt,
    const float* __restrict__ gf, const float* __restrict__ btf,
    const float* __restrict__ g2, const float* __restrict__ b2t, const float* __restrict__ b2f,
    const float* __restrict__ f1W, const float* __restrict__ f2W, bf16* __restrict__ w1)
{
    int bid = blockIdx.x;
    if (bid < 2048) ln2_body(bid, x1, h2, gt, btt, gf, btf, g2, b2t, b2f);
    else            cast_body((bid - 2048) * 256 + threadIdx.x, f1W, (HID * CC) / 4, f2W, w1);
}

// ------- BMxBN MFMA GEMM, single-barrier DEPTH-ring, counted vmcnt: C = A @ Bt^T -------
// SWZ=1 (T2, rule 21): linear LDS dest + inverse-swizzled global SOURCE + swizzled read
// (kept on HBM-streaming PROJ/OUT; off for L2-resident QKV/GELU).
// CASTN>0: grid.y extended past gyGemm; trailing blocks cast 589824 f32x4 items (one fc
// weight), CASTN items/thread — hides f-half weight casts under OUT-t / GELU-f tails.
enum { MODE_QKV = 0, MODE_PROJ = 1, MODE_GELU = 2, MODE_OUT = 3 };

template<int MODE, int K, int KCHUNK, int BM, int BN, int DEPTH, int SWZ, int CASTN>
__global__ __launch_bounds__(256, 3) void gemm_bt(
    const bf16* __restrict__ A, const bf16* __restrict__ Btb,
    const float* __restrict__ cbias, const float* residf,
    const float* __restrict__ gamma,
    bf16* __restrict__ outb0, bf16* __restrict__ outb1, bf16* __restrict__ outb2,
    float* outf, int rowbase,
    const float* __restrict__ castsrc, bf16* __restrict__ castdst, int gyGemm)
{
    constexpr int AR = BM / 64;    // staging rounds (256 threads x 16B covers 64 rows x 32 cols)
    constexpr int BR = BN / 64;
    constexpr int L  = AR + BR;    // vmem loads per tile per thread
    constexpr int VM = (DEPTH - 2) * L;  // counted: tile t landed, DEPTH-2 newer tiles in flight
    constexpr int NT = KCHUNK / 32;
    static_assert(NT > DEPTH, "");
    constexpr int FM = BM / 32;    // frags per wave (m)
    constexpr int FN = BN / 32;
    __shared__ bf16 lsA[DEPTH][BM * 32];
    __shared__ bf16 lsB[DEPTH][BN * 32];
    int tid = threadIdx.x;
    if (CASTN > 0 && (int)blockIdx.y >= gyGemm) {
        int cb = ((blockIdx.y - gyGemm) * gridDim.x + blockIdx.x) * gridDim.z + blockIdx.z;
        int base = cb * (256 * CASTN);
        #pragma unroll
        for (int i = 0; i < CASTN; i++)
            cast_body(base + i * 256 + tid, castsrc, 589824, nullptr, castdst);
        return;
    }
    int lane = tid & 63, w = tid >> 6;
    int wm = w & 1, wn = w >> 1;
    int gx = gridDim.x;
    int nwg = gx * gyGemm;
    int flat = blockIdx.y * gx + blockIdx.x;
    // XCD-aware bijective swizzle (nwg % 8 == 0 for every launch in this file)
    int cpx = nwg >> 3;
    flat = (flat & 7) * cpx + (flat >> 3);
    int bx = flat % gx, by = flat / gx;
    long m0 = (long)by * BM;
    long n0 = (long)bx * BN;
    long kb = (long)blockIdx.z * KCHUNK;
    f32x4 acc[FM][FN] = {};
    const bf16* Ab = A + m0 * K + kb;
    const bf16* Bb = Btb + n0 * K + kb;
    int r0 = tid >> 2;
    int la = lane & 15;
    // SWZ=0: natural chunk; SWZ=1: inverse-swizzled source / swizzled read (see header)
    int kgS = SWZ ? ((tid & 3) ^ ((tid >> 3) & 3)) * 8 : (tid & 3) * 8;
    int hkS = SWZ ? (((lane >> 4) ^ ((lane >> 1) & 3))) * 8 : (lane >> 4) * 8;

#define STAGE(DB, KT)                                                                        \
    {                                                                                        \
        long sk_ = (long)(KT) * 32;                                                          \
        _Pragma("unroll")                                                                    \
        for (int rr = 0; rr < AR; rr++)                                                      \
            g2l16(Ab + (long)(r0 + rr * 64) * K + sk_ + kgS, lsA[DB] + (tid + rr * 256) * 8);\
        _Pragma("unroll")                                                                    \
        for (int rr = 0; rr < BR; rr++)                                                      \
            g2l16(Bb + (long)(r0 + rr * 64) * K + sk_ + kgS, lsB[DB] + (tid + rr * 256) * 8);\
    }

    // prologue: stage tiles 0..DEPTH-2 (one ring slot stays free), no waits
    #pragma unroll
    for (int d = 0; d < DEPTH - 1; d++) STAGE(d, d)

    int p = 0;
    for (int t = 0; t < NT - 1; t++) {
        wait_vm<VM>();                          // my share of tile t landed
        __builtin_amdgcn_sched_barrier(0);
        __builtin_amdgcn_s_barrier();           // everyone's share landed; t-1 reads retired
        __builtin_amdgcn_sched_barrier(0);
        bf16x8 af[FM], bfr[FN];
        #pragma unroll
        for (int mi = 0; mi < FM; mi++) af[mi]  = *(bf16x8*)&lsA[p][(wm * (BM / 2) + mi * 16 + la) * 32 + hkS];
        #pragma unroll
        for (int ni = 0; ni < FN; ni++) bfr[ni] = *(bf16x8*)&lsB[p][(wn * (BN / 2) + ni * 16 + la) * 32 + hkS];
        if (t + DEPTH - 1 < NT) {
            int pd = p + DEPTH - 1; if (pd >= DEPTH) pd -= DEPTH;   // buffer freed at t-1
            STAGE(pd, t + DEPTH - 1)
        }
        asm volatile("s_waitcnt lgkmcnt(0)" ::: "memory");
        __builtin_amdgcn_sched_barrier(0);
        __builtin_amdgcn_s_setprio(1);
        #pragma unroll
        for (int mi = 0; mi < FM; mi++)
            #pragma unroll
            for (int ni = 0; ni < FN; ni++)
                acc[mi][ni] = mfma16(af[mi], bfr[ni], acc[mi][ni]);
        __builtin_amdgcn_s_setprio(0);
        p = (p + 1 == DEPTH) ? 0 : p + 1;
    }
    // last iteration: nothing left in flight to count -> full drain
    {
        wait_vm<0>();
        __builtin_amdgcn_sched_barrier(0);
        __builtin_amdgcn_s_barrier();
        __builtin_amdgcn_sched_barrier(0);
        bf16x8 af[FM], bfr[FN];
        #pragma unroll
        for (int mi = 0; mi < FM; mi++) af[mi]  = *(bf16x8*)&lsA[p][(wm * (BM / 2) + mi * 16 + la) * 32 + hkS];
        #pragma unroll
        for (int ni = 0; ni < FN; ni++) bfr[ni] = *(bf16x8*)&lsB[p][(wn * (BN / 2) + ni * 16 + la) * 32 + hkS];
        asm volatile("s_waitcnt lgkmcnt(0)" ::: "memory");
        __builtin_amdgcn_sched_barrier(0);
        __builtin_amdgcn_s_setprio(1);
        #pragma unroll
        for (int mi = 0; mi < FM; mi++)
            #pragma unroll
            for (int ni = 0; ni < FN; ni++)
                acc[mi][ni] = mfma16(af[mi], bfr[ni], acc[mi][ni]);
        __builtin_amdgcn_s_setprio(0);
    }
#undef STAGE

    int q4 = (lane >> 4) * 4;
    // QKV: the whole block maps into exactly one of q/k/v (768 % BN == 0)
    int sblk = 0, cb0 = 0;
    if constexpr (MODE == MODE_QKV) {
        sblk = (int)(n0 / CC);
        cb0  = (int)n0 - sblk * CC;
    }
    #pragma unroll
    for (int mi = 0; mi < FM; mi++) {
        #pragma unroll
        for (int ni = 0; ni < FN; ni++) {
            long rb = m0 + wm * (BM / 2) + mi * 16 + q4;
            long c  = n0 + wn * (BN / 2) + ni * 16 + la;
            #pragma unroll
            for (int i = 0; i < 4; i++) {
                long r = rb + i;
                float v = acc[mi][ni][i];
                if (MODE == MODE_QKV) {
                    int rem = cb0 + wn * (BN / 2) + ni * 16 + la;
                    int hh = rem >> 6, d = rem & 63;
                    long b = r >> 9, n = r & 511;
                    long dst = (((b * HH + hh) << 9) + n) * 64 + d;
                    if (sblk == 0)      outb0[dst] = (bf16)(v * 0.125f);
                    else if (sblk == 1) outb1[dst] = (bf16)v;
                    else                outb2[dst] = (bf16)v;
                } else if (MODE == MODE_PROJ) {
                    float val = v + cbias[c];
                    long idx = r * CC + c;
                    outf[idx] = residf[idx] + gamma[c] * val;
                } else if (MODE == MODE_GELU) {
                    float val = v + cbias[c];
                    float gl = 0.5f * val * (1.f + erff(val * 0.70710678118f));
                    outb0[r * (long)HID + c] = (bf16)gl;
                } else {  // MODE_OUT: bias pre-added by ln2 writeback; split-K atomic accumulate
                    long grow = (r >> 8) * NN + (r & 255) + rowbase;
                    atomicAdd(outf + grow * CC + c, gamma[c] * v);
                }
            }
        }
    }
}

// ---------------- Flash attention: 128 q-rows per block (two 16-row tiles per wave) ----------------
// grid = b(16) x qt(4) x h(12).  K/V staged once per chunk, reused by both q-sets.
// bias read as 2x16B coalesced loads from pre-arranged fragment layout.
// row-sum l accumulated via mfma(P, ones) (rides the MFMA pipe; no sum-shuffles).
__global__ __launch_bounds__(256, 3) void attn_kernel(
    const bf16* __restrict__ q, const bf16* __restrict__ k, const bf16* __restrict__ v,
    const bf16* __restrict__ bb, bf16* __restrict__ o)
{
    __shared__ bf16 lsK[64 * 72];
    __shared__ bf16 lsVT[64 * 68];
    __shared__ bf16 lsP[4][2][16 * 76];
    int tid = threadIdx.x, lane = tid & 63, w = tid >> 6;
    int b  = blockIdx.x & 15;
    int qt = (blockIdx.x >> 4) & 3;
    int h  = blockIdx.x >> 6;
    long base = (long)(b * HH + h) * NN * DD;
    int la = lane & 15, hi = lane >> 4;
    int qr0 = qt * 128 + w * 16;           // set A rows; set B = +64
    // bias base for (h, granule=qt*2, w); granule stride = 4*8*1024 = 32768
    const bf16* bb0 = bb + ((long)((h * 8 + qt * 2) * 4 + w) * 8) * 1024 + lane * 16;

    bf16x8 qA0 = *(const bf16x8*)&q[base + (long)(qr0 + la) * 64 + hi * 8];
    bf16x8 qA1 = *(const bf16x8*)&q[base + (long)(qr0 + la) * 64 + 32 + hi * 8];
    bf16x8 qB0 = *(const bf16x8*)&q[base + (long)(qr0 + 64 + la) * 64 + hi * 8];
    bf16x8 qB1 = *(const bf16x8*)&q[base + (long)(qr0 + 64 + la) * 64 + 32 + hi * 8];
    f32x4 ofA[4] = {}, ofB[4] = {};
    f32x4 lfA = {}, lfB = {};
    float mA[4], mB[4];
    #pragma unroll
    for (int i = 0; i < 4; i++) { mA[i] = -1e30f; mB[i] = -1e30f; }
    bf16x8 ones;
    #pragma unroll
    for (int e = 0; e < 8; e++) ones[e] = (bf16)1.0f;

    int jr = tid >> 2, dg16 = (tid & 3) * 16;
    for (int ch = 0; ch < 8; ch++) {
        int j0 = ch * 64;
        const bf16* krow = &k[base + (long)(j0 + jr) * 64 + dg16];
        *(bf16x8*)&lsK[jr * 72 + dg16]     = *(const bf16x8*)krow;
        *(bf16x8*)&lsK[jr * 72 + dg16 + 8] = *(const bf16x8*)(krow + 8);
        const bf16* vrow = &v[base + (long)(j0 + jr) * 64 + dg16];
        bf16x8 v0 = *(const bf16x8*)vrow;
        bf16x8 v1 = *(const bf16x8*)(vrow + 8);
        #pragma unroll
        for (int e = 0; e < 8; e++) {
            lsVT[(dg16 + e) * 68 + jr]     = v0[e];
            lsVT[(dg16 + 8 + e) * 68 + jr] = v1[e];
        }
        __syncthreads();

        // QK^T, K-frags shared by both q-sets
        f32x4 sA[4] = {}, sB[4] = {};
        #pragma unroll
        for (int t = 0; t < 4; t++) {
            bf16x8 kf0 = *(bf16x8*)&lsK[(t * 16 + la) * 72 + hi * 8];
            bf16x8 kf1 = *(bf16x8*)&lsK[(t * 16 + la) * 72 + 32 + hi * 8];
            sA[t] = mfma16(qA0, kf0, sA[t]);
            sA[t] = mfma16(qA1, kf1, sA[t]);
            sB[t] = mfma16(qB0, kf0, sB[t]);
            sB[t] = mfma16(qB1, kf1, sB[t]);
        }
        // bias: 2x16B coalesced loads per set
        {
            const bf16* bpA = bb0 + ch * 1024;
            const bf16* bpB = bpA + 32768;
            bf16x8 a0 = *(const bf16x8*)bpA, a1 = *(const bf16x8*)(bpA + 8);
            bf16x8 c0 = *(const bf16x8*)bpB, c1 = *(const bf16x8*)(bpB + 8);
            #pragma unroll
            for (int t = 0; t < 4; t++) {
                sA[t][0] += (float)a0[t];     sA[t][1] += (float)a0[4 + t];
                sA[t][2] += (float)a1[t];     sA[t][3] += (float)a1[4 + t];
                sB[t][0] += (float)c0[t];     sB[t][1] += (float)c0[4 + t];
                sB[t][2] += (float)c1[t];     sB[t][3] += (float)c1[4 + t];
            }
        }
        // online softmax (max-reduce via shuffles; sum deferred to mfma(P, ones))
        #define SM_SET(S, M, OF, LF, PSET)                                               \
        {                                                                                \
            float alpha[4];                                                              \
            _Pragma("unroll")                                                            \
            for (int i = 0; i < 4; i++) {                                                \
                float mx = fmaxf(fmaxf(S[0][i], S[1][i]), fmaxf(S[2][i], S[3][i]));      \
                _Pragma("unroll")                                                        \
                for (int msk = 1; msk < 16; msk <<= 1) mx = fmaxf(mx, __shfl_xor(mx, msk)); \
                float mn = fmaxf(M[i], mx);                                              \
                alpha[i] = __expf(M[i] - mn);                                            \
                M[i] = mn;                                                               \
                _Pragma("unroll")                                                        \
                for (int t = 0; t < 4; t++) S[t][i] = __expf(S[t][i] - mn);              \
            }                                                                            \
            _Pragma("unroll")                                                            \
            for (int t = 0; t < 4; t++) {                                                \
                _Pragma("unroll")                                                        \
                for (int i = 0; i < 4; i++) OF[t][i] *= alpha[i];                        \
            }                                                                            \
            _Pragma("unroll")                                                            \
            for (int i = 0; i < 4; i++) LF[i] *= alpha[i];                               \
            _Pragma("unroll")                                                            \
            for (int i = 0; i < 4; i++) {                                                \
                _Pragma("unroll")                                                        \
                for (int t = 0; t < 4; t++)                                              \
                    lsP[w][PSET][(hi * 4 + i) * 76 + t * 16 + la] = (bf16)S[t][i];       \
            }                                                                            \
        }
        SM_SET(sA, mA, ofA, lfA, 0)
        SM_SET(sB, mB, ofB, lfB, 1)
        #undef SM_SET

        bf16x8 pA0 = *(bf16x8*)&lsP[w][0][la * 76 + hi * 8];
        bf16x8 pA1 = *(bf16x8*)&lsP[w][0][la * 76 + 32 + hi * 8];
        bf16x8 pB0 = *(bf16x8*)&lsP[w][1][la * 76 + hi * 8];
        bf16x8 pB1 = *(bf16x8*)&lsP[w][1][la * 76 + 32 + hi * 8];
        #pragma unroll
        for (int t = 0; t < 4; t++) {
            bf16x8 vf0 = *(bf16x8*)&lsVT[(t * 16 + la) * 68 + hi * 8];
            bf16x8 vf1 = *(bf16x8*)&lsVT[(t * 16 + la) * 68 + 32 + hi * 8];
            ofA[t] = mfma16(pA0, vf0, ofA[t]);
            ofA[t] = mfma16(pA1, vf1, ofA[t]);
            ofB[t] = mfma16(pB0, vf0, ofB[t]);
            ofB[t] = mfma16(pB1, vf1, ofB[t]);
        }
        lfA = mfma16(pA0, ones, lfA);
        lfA = mfma16(pA1, ones, lfA);
        lfB = mfma16(pB0, ones, lfB);
        lfB = mfma16(pB1, ones, lfB);
        __syncthreads();
    }
    float invA[4], invB[4];
    #pragma unroll
    for (int i = 0; i < 4; i++) { invA[i] = 1.f / lfA[i]; invB[i] = 1.f / lfB[i]; }
    #pragma unroll
    for (int t = 0; t < 4; t++) {
        #pragma unroll
        for (int i = 0; i < 4; i++) {
            long rowA = (long)b * NN + qr0 + hi * 4 + i;
            o[rowA * CC + h * 64 + t * 16 + la]        = (bf16)(ofA[t][i] * invA[i]);
            o[(rowA + 64) * CC + h * 64 + t * 16 + la] = (bf16)(ofB[t][i] * invB[i]);
        }
    }
}

extern "C" void kernel_launch(void* const* d_in, const int* in_sizes, int n_in,
                              void* d_out, int out_size, void* d_ws, size_t ws_size,
                              hipStream_t stream)
{
    const float* x     = (const float*)d_in[0];
    const int*   rpi   = (const int*)d_in[2];
    const float* Wqkv  = (const float*)d_in[3];
    const float* Wproj = (const float*)d_in[4];
    const float* bproj = (const float*)d_in[5];
    const float* rtab  = (const float*)d_in[6];
    const float* ln1g  = (const float*)d_in[7];
    const float* ln1b  = (const float*)d_in[8];
    const float* g1    = (const float*)d_in[9];
    const float* g2    = (const float*)d_in[10];
    const float* ln2tg = (const float*)d_in[11];
    const float* ln2tb = (const float*)d_in[12];
    const float* f1tW  = (const float*)d_in[13];
    const float* f1tb  = (const float*)d_in[14];
    const float* f2tW  = (const float*)d_in[15];
    const float* f2tb  = (const float*)d_in[16];
    const float* ln2fg = (const float*)d_in[17];
    const float* ln2fb = (const float*)d_in[18];
    const float* f1fW  = (const float*)d_in[19];
    const float* f1fb  = (const float*)d_in[20];
    const float* f2fW  = (const float*)d_in[21];
    const float* f2fb  = (const float*)d_in[22];
    float* out = (float*)d_out;

    // ws: 4 regions x 12.58MB bf16 = 50.33MB.
    //  rA: q -> wpro -> h2 (w1f cast over dead t-half during OUT-t)
    //  rB: k -> hg lo     rC: v -> hg hi
    //  rD: Wqkv(bf16) -> o -> [w1t|w2t] -> w2f over dead w1t during GELU-f
    // d_out: [0,12.6MB) h; [12.6,18.9MB) bias table; then x1 (fp32) overwrites all
    char* ws = (char*)d_ws;
    const long TOKC = (long)BB * NN * CC;        // 6291456
    const int  NFC  = HID * CC;                  // 2359296
    bf16* rA = (bf16*)ws;
    bf16* rB = rA + TOKC;
    bf16* rC = rB + TOKC;
    bf16* rD = rC + TOKC;

    bf16 *qb = rA, *kb = rB, *vb = rC, *o = rD;
    bf16  *h    = (bf16*)d_out;
    bf16  *bbt  = h + TOKC;        // coexists with h (d_out is 25.2MB fp32 out)
    float *x1   = out;
    bf16  *wqkv = rD;     // before o
    bf16  *wpro = rA;     // after q dies
    bf16  *h2   = rA;     // after wpro dies
    bf16  *hg   = rB;     // spans rB+rC
    bf16  *w1t  = rD;     // [w1t | w2t] pair cast by ln2_cast (o dead)
    bf16  *w2t  = rD + NFC;
    bf16  *w1f  = rA;     // cast into dead t-half h2 region during OUT-t
    bf16  *w2f  = rD;     // cast over dead w1t during GELU-f

    // 1. LN1 (fp32 x -> bf16 h) + Wqkv cast (rD) + bias table (d_out+12.6MB) in one launch
    ln1_cast_kernel<<<2048 + 1728 + 768, 256, 0, stream>>>(x, h, ln1g, ln1b, Wqkv, wqkv, rpi, rtab, bbt);
    // 2. QKV projection (L2-resident: SWZ=0)
    {
        dim3 g(2304 / 128, 8192 / 128, 1);
        gemm_bt<MODE_QKV, 768, 768, 128, 128, 3, 0, 0><<<g, 256, 0, stream>>>(
            h, wqkv, nullptr, nullptr, nullptr, qb, kb, vb, nullptr, 0, nullptr, nullptr, 64);
    }
    // 3. attention (reads rA,rB,rC,bbt; writes o=rD; wqkv dead)
    attn_kernel<<<BB * 4 * HH, 256, 0, stream>>>(qb, kb, vb, bbt, o);
    // 4. cast Wproj -> bf16 (rA; q dead)
    cast2_kernel<<<576, 256, 0, stream>>>(Wproj, 147456, nullptr, wpro);
    // 5. proj + residual -> x1 (HBM-streaming: SWZ=1); 64x128 tile -> 768 blocks (3/CU)
    {
        dim3 g(768 / 128, 8192 / 64, 1);
        gemm_bt<MODE_PROJ, 768, 768, 64, 128, 4, 1, 0><<<g, 256, 0, stream>>>(
            o, wpro, bproj, x, g1, nullptr, nullptr, nullptr, x1, 0, nullptr, nullptr, 128);
    }
    // 6. LN2 both halves -> h2 (rA; wpro dead), x1 += g2*fc2_bias; cast (f1tW,f2tW) -> rD
    ln2_cast_kernel<<<2048 + 4608, 256, 0, stream>>>(x1, h2, ln2tg, ln2tb, ln2fg, ln2fb, g2, f2tb, f2fb,
                                                     f1tW, f2tW, w1t);
    // 7. GELU-t (SWZ=0): h2[0:4096] @ w1t -> hg
    {
        dim3 ga(3072 / 128, 4096 / 128, 1);
        gemm_bt<MODE_GELU, 768, 768, 128, 128, 3, 0, 0><<<ga, 256, 0, stream>>>(
            h2, w1t, f1tb, nullptr, nullptr, hg, nullptr, nullptr, nullptr, 0, nullptr, nullptr, 32);
    }
    // 8. OUT-t (SWZ=1, split-K=2) + folded w1f cast -> rA (t-half h2 dead after GELU-t):
    //    grid (6, 64 gemm + 64 cast, 2); cast blocks = 6*64*2 = 768, 3 items/thread.
    {
        dim3 gb(768 / 128, 64 + 64, 2);
        gemm_bt<MODE_OUT, 3072, 1536, 64, 128, 4, 1, 3><<<gb, 256, 0, stream>>>(
            hg, w2t, nullptr, nullptr, g2, nullptr, nullptr, nullptr, out, 0, f1fW, w1f, 64);
    }
    // 9. GELU-f (SWZ=0) + folded w2f cast -> rD[0] (w1t dead after GELU-t):
    //    grid (24, 32 gemm + 12 cast); cast blocks = 24*12 = 288, 8 items/thread.
    {
        dim3 ga(3072 / 128, 32 + 12, 1);
        gemm_bt<MODE_GELU, 768, 768, 128, 128, 3, 0, 8><<<ga, 256, 0, stream>>>(
            h2 + (long)4096 * CC, w1f, f1fb, nullptr, nullptr, hg, nullptr, nullptr, nullptr, 0, f2fW, w2f, 32);
    }
    // 10. OUT-f (SWZ=1, split-K=2), B = w2f at rD[0]
    {
        dim3 gb(768 / 128, 4096 / 64, 2);
        gemm_bt<MODE_OUT, 3072, 1536, 64, 128, 4, 1, 0><<<gb, 256, 0, stream>>>(
            hg, w2f, nullptr, nullptr, g2, nullptr, nullptr, nullptr, out, 256, nullptr, nullptr, 64);
    }
}